// Round 2
// baseline (39000.616 us; speedup 1.0000x reference)
//
#include <hip/hip_runtime.h>
#include <cstdint>
#include <cstddef>

namespace {

constexpr int H    = 300;
constexpr int G4   = 1200;   // 4*H
constexpr int B    = 128;
constexpr int T    = 512;
constexpr int NVOC = 2514;

// ---------------------------------------------------------------------------
// Tiled fp32 GEMM:  out[m][n] = sum_k A[row(m)][k] * W[n][k] + b1[n] (+ b2[n])
// AMODE 0: row = m
// AMODE 1: row = tok[(m&127)*512 + (m>>7)]   (embedding gather, m = t*128+b)
// AMODE 2: row = (m&127)*512 + (m>>7)        ([t,b] -> [b,t] permute)
// (unchanged from round 1 — not the bottleneck; ~2.3 ms of 26.7)
// ---------------------------------------------------------------------------
template<int AMODE, bool HASB2>
__global__ __launch_bounds__(256)
void gemm_tn(const float* __restrict__ A, const float* __restrict__ W,
             const float* __restrict__ b1, const float* __restrict__ b2,
             const int* __restrict__ tok, float* __restrict__ out, int N)
{
    constexpr int K = 300;
    __shared__ __align__(16) float as[8][128];
    __shared__ __align__(16) float bs[8][128];

    const int tid = threadIdx.x;
    const int tx = tid & 15, ty = tid >> 4;
    const int m0 = blockIdx.y * 128;
    const int n0 = blockIdx.x * 128;
    const int rl  = tid >> 1;
    const int kk0 = (tid & 1) * 4;

    const int m = m0 + rl;
    int arow;
    if (AMODE == 0) {
        arow = m;
    } else {
        const int q = ((m & 127) << 9) + (m >> 7);
        arow = (AMODE == 1) ? tok[q] : q;
    }
    const float* aptr = A + (size_t)arow * K;
    const int nrow = n0 + rl;
    const float* wptr = W + (size_t)nrow * K;
    const bool nvalid = (nrow < N);

    float acc[8][8];
#pragma unroll
    for (int i = 0; i < 8; ++i)
#pragma unroll
        for (int j = 0; j < 8; ++j) acc[i][j] = 0.f;

    for (int k0 = 0; k0 < K; k0 += 8) {
        float4 av = make_float4(0.f, 0.f, 0.f, 0.f);
        float4 bv = make_float4(0.f, 0.f, 0.f, 0.f);
        const bool kv = (k0 + kk0 < K);
        if (kv)           av = *(const float4*)(aptr + k0 + kk0);
        if (kv && nvalid) bv = *(const float4*)(wptr + k0 + kk0);
        __syncthreads();
        as[kk0+0][rl] = av.x; as[kk0+1][rl] = av.y; as[kk0+2][rl] = av.z; as[kk0+3][rl] = av.w;
        bs[kk0+0][rl] = bv.x; bs[kk0+1][rl] = bv.y; bs[kk0+2][rl] = bv.z; bs[kk0+3][rl] = bv.w;
        __syncthreads();
#pragma unroll
        for (int kk = 0; kk < 8; ++kk) {
            float4 a0 = *(const float4*)&as[kk][ty*8];
            float4 a1 = *(const float4*)&as[kk][ty*8+4];
            float4 c0 = *(const float4*)&bs[kk][tx*8];
            float4 c1 = *(const float4*)&bs[kk][tx*8+4];
            float a[8] = {a0.x,a0.y,a0.z,a0.w,a1.x,a1.y,a1.z,a1.w};
            float b[8] = {c0.x,c0.y,c0.z,c0.w,c1.x,c1.y,c1.z,c1.w};
#pragma unroll
            for (int i = 0; i < 8; ++i)
#pragma unroll
                for (int j = 0; j < 8; ++j)
                    acc[i][j] = fmaf(a[i], b[j], acc[i][j]);
        }
    }

    float bias[8];
#pragma unroll
    for (int j = 0; j < 8; ++j) {
        const int n = n0 + tx*8 + j;
        float v = 0.f;
        if (n < N) { v = b1[n]; if (HASB2) v += b2[n]; }
        bias[j] = v;
    }
#pragma unroll
    for (int i = 0; i < 8; ++i) {
        const int mi = m0 + ty*8 + i;
        float* orow = out + (size_t)mi * N + n0 + tx*8;
#pragma unroll
        for (int j = 0; j < 8; j += 2) {
            const int n = n0 + tx*8 + j;
            if (n + 1 < N) {
                *(float2*)(orow + j) = make_float2(acc[i][j] + bias[j],
                                                   acc[i][j+1] + bias[j+1]);
            } else if (n < N) {
                orow[j] = acc[i][j] + bias[j];
            }
        }
    }
}

// ---------------------------------------------------------------------------
// Persistent LSTM recurrence v2.
// 240 blocks = 15 hidden-groups x 16 batch-groups, 256 threads (4 waves).
// Per block: 80 gate-cols (20 hidden units x 4 gates) x 8 batch rows.
// Per step:
//   - 4 waves k-split (76 k each, K padded 300->304), lane = (gg 0..15, bb 0..3),
//     per-lane tile 5 gates x 2 batch, all LDS reads ds_read_b128 with
//     broadcast reuse (16 lanes share each h address, 4 share each w address).
//     LDS pitch 308: every pattern <=2-way (free).
//   - k-partials reduced via small LDS array, activations + private cell state.
//   - flag-array grid barrier: arrival = one release-store to own slot (no RMW
//     contention); wait = 240 threads each polling one distinct word.
//   - h staging uses plain float4 loads: h_all[b][t] lines are write-once
//     (producer stores are agent-scope write-through) and values are
//     replay-deterministic, so L1/L2 reuse across replays is benign.
// ---------------------------------------------------------------------------
constexpr int HGC = 15;    // hidden groups
constexpr int BGC = 16;    // batch groups
constexpr int NWG = HGC * BGC;   // 240
constexpr int HS  = 20;    // hidden units per block
constexpr int BS  = 8;     // batch rows per block
constexpr int LTH = 256;
constexpr int WP  = 308;   // LDS pitch (floats): 16B-aligned rows, <=2-way banks
constexpr int LDSF = 80*WP + BS*WP + 4*BS*80;   // W + h + partials (floats)

__device__ __forceinline__ float sigm(float x)     { return 1.f / (1.f + __expf(-x)); }
__device__ __forceinline__ float tanhfast(float x) { return 1.f - 2.f / (__expf(2.f*x) + 1.f); }

__global__ __launch_bounds__(LTH)
void lstm_layer_k(const float* __restrict__ xg, const float* __restrict__ Whh,
                  float* __restrict__ h_all, unsigned* __restrict__ flags)
{
    extern __shared__ float smem[];
    float (*w_lds)[WP] = (float(*)[WP])smem;                       // [80][308]
    float (*h_lds)[WP] = (float(*)[WP])(smem + 80*WP);             // [8][308]
    float (*gp)[BS][80] = (float(*)[BS][80])(smem + 80*WP + BS*WP);// [4][8][80]

    const int tid = threadIdx.x;
    const int hg  = blockIdx.x % HGC;
    const int bg  = blockIdx.x / HGC;

    // zero all LDS (establishes k-pad zeros and t=0 h state), then stage W
    for (int i = tid; i < LDSF; i += LTH) smem[i] = 0.f;
    __syncthreads();
    for (int idx = tid; idx < 80*75; idx += LTH) {
        const int r = idx / 75, q = (idx % 75) * 4;
        const int jglob = (r / HS) * H + hg * HS + (r % HS);
        *(float4*)&w_lds[r][q] = *(const float4*)(Whh + (size_t)jglob * H + q);
    }
    __syncthreads();

    const int lane = tid & 63;
    const int kc   = tid >> 6;          // wave id = k-chunk
    const int gg   = lane & 15;         // gate group (x5)
    const int bb   = lane >> 4;         // batch group (x2)
    const int k0   = kc * 76;

    const float* wr0 = &w_lds[gg*5+0][k0];
    const float* wr1 = &w_lds[gg*5+1][k0];
    const float* wr2 = &w_lds[gg*5+2][k0];
    const float* wr3 = &w_lds[gg*5+3][k0];
    const float* wr4 = &w_lds[gg*5+4][k0];
    const float* hr0 = &h_lds[bb*2+0][k0];
    const float* hr1 = &h_lds[bb*2+1][k0];

    const int ub = tid / HS;            // update thread -> batch row (tid<160)
    const int ul = tid % HS;            // update thread -> hidden unit
    float c = 0.f;                      // private cell state

    for (int t = 0; t < T; ++t) {
        // ---- xg prefetch for the update phase (no deps; overlaps the wait) ----
        float xr0 = 0.f, xr1 = 0.f, xr2 = 0.f, xr3 = 0.f;
        if (tid < BS*HS) {
            const float* xb = xg + ((size_t)t * B + bg*BS + ub) * G4 + hg*HS + ul;
            xr0 = xb[0*H]; xr1 = xb[1*H]; xr2 = xb[2*H]; xr3 = xb[3*H];
        }

        if (t > 0) {
            // ---- wait for all blocks to publish h[t-1] ----
            if (tid < NWG) {
                while (__hip_atomic_load(&flags[tid], __ATOMIC_ACQUIRE,
                                         __HIP_MEMORY_SCOPE_AGENT) < (unsigned)t)
                    __builtin_amdgcn_s_sleep(8);
            }
            __syncthreads();
            // ---- stage h[t-1] for our 8 batch rows (vector loads) ----
            for (int idx = tid; idx < BS*75; idx += LTH) {
                const int b = idx / 75, q = (idx % 75) * 4;
                *(float4*)&h_lds[b][q] =
                    *(const float4*)(h_all + ((size_t)(bg*BS + b) * T + (t-1)) * H + q);
            }
        }
        __syncthreads();

        // ---- k-chunk partial matmul: 5 gates x 2 batch per lane ----
        float a00=0.f,a01=0.f,a10=0.f,a11=0.f,a20=0.f,a21=0.f,a30=0.f,a31=0.f,a40=0.f,a41=0.f;
        for (int ki = 0; ki < 19; ++ki) {
            const float4 h0 = *(const float4*)(hr0 + ki*4);
            const float4 h1 = *(const float4*)(hr1 + ki*4);
            float4 w;
            w = *(const float4*)(wr0 + ki*4);
            a00 += w.x*h0.x + w.y*h0.y + w.z*h0.z + w.w*h0.w;
            a01 += w.x*h1.x + w.y*h1.y + w.z*h1.z + w.w*h1.w;
            w = *(const float4*)(wr1 + ki*4);
            a10 += w.x*h0.x + w.y*h0.y + w.z*h0.z + w.w*h0.w;
            a11 += w.x*h1.x + w.y*h1.y + w.z*h1.z + w.w*h1.w;
            w = *(const float4*)(wr2 + ki*4);
            a20 += w.x*h0.x + w.y*h0.y + w.z*h0.z + w.w*h0.w;
            a21 += w.x*h1.x + w.y*h1.y + w.z*h1.z + w.w*h1.w;
            w = *(const float4*)(wr3 + ki*4);
            a30 += w.x*h0.x + w.y*h0.y + w.z*h0.z + w.w*h0.w;
            a31 += w.x*h1.x + w.y*h1.y + w.z*h1.z + w.w*h1.w;
            w = *(const float4*)(wr4 + ki*4);
            a40 += w.x*h0.x + w.y*h0.y + w.z*h0.z + w.w*h0.w;
            a41 += w.x*h1.x + w.y*h1.y + w.z*h1.z + w.w*h1.w;
        }
        gp[kc][bb*2+0][gg*5+0] = a00;  gp[kc][bb*2+1][gg*5+0] = a01;
        gp[kc][bb*2+0][gg*5+1] = a10;  gp[kc][bb*2+1][gg*5+1] = a11;
        gp[kc][bb*2+0][gg*5+2] = a20;  gp[kc][bb*2+1][gg*5+2] = a21;
        gp[kc][bb*2+0][gg*5+3] = a30;  gp[kc][bb*2+1][gg*5+3] = a31;
        gp[kc][bb*2+0][gg*5+4] = a40;  gp[kc][bb*2+1][gg*5+4] = a41;
        __syncthreads();

        // ---- reduce + activations + cell update (one (b,l) per thread) ----
        if (tid < BS*HS) {
            const float g0 = xr0 + gp[0][ub][0*HS+ul] + gp[1][ub][0*HS+ul]
                                 + gp[2][ub][0*HS+ul] + gp[3][ub][0*HS+ul];
            const float g1 = xr1 + gp[0][ub][1*HS+ul] + gp[1][ub][1*HS+ul]
                                 + gp[2][ub][1*HS+ul] + gp[3][ub][1*HS+ul];
            const float g2 = xr2 + gp[0][ub][2*HS+ul] + gp[1][ub][2*HS+ul]
                                 + gp[2][ub][2*HS+ul] + gp[3][ub][2*HS+ul];
            const float g3 = xr3 + gp[0][ub][3*HS+ul] + gp[1][ub][3*HS+ul]
                                 + gp[2][ub][3*HS+ul] + gp[3][ub][3*HS+ul];
            const float iG = sigm(g0), fG = sigm(g1), gG = tanhfast(g2), oG = sigm(g3);
            c = fmaf(fG, c, iG * gG);
            const float hv = oG * tanhfast(c);
            float* p = h_all + ((size_t)(bg*BS + ub) * T + t) * H + hg*HS + ul;
            __hip_atomic_store(p, hv, __ATOMIC_RELAXED, __HIP_MEMORY_SCOPE_AGENT);
            __threadfence();   // h stores visible agent-wide before flag publish
        }
        __syncthreads();
        if (tid == 0)
            __hip_atomic_store(&flags[blockIdx.x], (unsigned)(t + 1),
                               __ATOMIC_RELEASE, __HIP_MEMORY_SCOPE_AGENT);
    }
}

} // anonymous namespace

// ---------------------------------------------------------------------------
extern "C" void kernel_launch(void* const* d_in, const int* in_sizes, int n_in,
                              void* d_out, int out_size, void* d_ws, size_t ws_size,
                              hipStream_t stream)
{
    const int*   x    = (const int*)  d_in[0];
    const float* emb  = (const float*)d_in[1];
    const float* Wih0 = (const float*)d_in[2];
    const float* Whh0 = (const float*)d_in[3];
    const float* bih0 = (const float*)d_in[4];
    const float* bhh0 = (const float*)d_in[5];
    const float* Wih1 = (const float*)d_in[6];
    const float* Whh1 = (const float*)d_in[7];
    const float* bih1 = (const float*)d_in[8];
    const float* bhh1 = (const float*)d_in[9];
    const float* Wout = (const float*)d_in[10];
    const float* bout = (const float*)d_in[11];

    float* out = (float*)d_out;
    // xg [T][B][4H] fp32 (315 MB) aliases the output buffer (659 MB): fully
    // consumed before the final GEMM overwrites d_out.
    float* xg = (float*)d_out;
    float* h1 = (float*)d_ws;                       // [B][T][H] fp32, 78.6 MB
    float* h2 = h1 + (size_t)B * T * H;             // 78.6 MB
    unsigned* flags = (unsigned*)((char*)d_ws + 2 * (size_t)B * T * H * sizeof(float));

    hipMemsetAsync(flags, 0, 2 * 256 * sizeof(unsigned), stream);

    constexpr size_t lstm_lds = (size_t)LDSF * sizeof(float);   // 118,656 B
    static_assert(lstm_lds < 160*1024, "LDS over budget");
    hipFuncSetAttribute(reinterpret_cast<const void*>(lstm_layer_k),
                        hipFuncAttributeMaxDynamicSharedMemorySize, (int)lstm_lds);

    const dim3 blk(256);
    // L0 input projection (embedding gather fused)
    gemm_tn<1, true ><<<dim3(10, 512), blk, 0, stream>>>(emb, Wih0, bih0, bhh0, x, xg, G4);
    // L0 recurrence
    lstm_layer_k<<<dim3(NWG), dim3(LTH), lstm_lds, stream>>>(xg, Whh0, h1, flags);
    // L1 input projection ([b][t] -> [t][b] permute fused)
    gemm_tn<2, true ><<<dim3(10, 512), blk, 0, stream>>>(h1, Wih1, bih1, bhh1, nullptr, xg, G4);
    // L1 recurrence
    lstm_layer_k<<<dim3(NWG), dim3(LTH), lstm_lds, stream>>>(xg, Whh1, h2, flags + 256);
    // output projection -> logits [b*T+t][NVOC]
    gemm_tn<0, false><<<dim3(20, 512), blk, 0, stream>>>(h2, Wout, bout, nullptr, nullptr, out, NVOC);
}

// Round 3
// 10802.009 us; speedup vs baseline: 3.6105x; 3.6105x over previous
//
#include <hip/hip_runtime.h>
#include <cstdint>
#include <cstddef>

namespace {

constexpr int H    = 300;
constexpr int G4   = 1200;   // 4*H
constexpr int B    = 128;
constexpr int T    = 512;
constexpr int NVOC = 2514;

// ---------------------------------------------------------------------------
// Tiled fp32 GEMM:  out[m][n] = sum_k A[row(m)][k] * W[n][k] + b1[n] (+ b2[n])
// AMODE 0: row = m
// AMODE 1: row = tok[(m&127)*512 + (m>>7)]   (embedding gather, m = t*128+b)
// AMODE 2: row = (m&127)*512 + (m>>7)        ([t,b] -> [b,t] permute)
// (unchanged — ~2.3 ms of the 39 ms total; not this round's bottleneck)
// ---------------------------------------------------------------------------
template<int AMODE, bool HASB2>
__global__ __launch_bounds__(256)
void gemm_tn(const float* __restrict__ A, const float* __restrict__ W,
             const float* __restrict__ b1, const float* __restrict__ b2,
             const int* __restrict__ tok, float* __restrict__ out, int N)
{
    constexpr int K = 300;
    __shared__ __align__(16) float as[8][128];
    __shared__ __align__(16) float bs[8][128];

    const int tid = threadIdx.x;
    const int tx = tid & 15, ty = tid >> 4;
    const int m0 = blockIdx.y * 128;
    const int n0 = blockIdx.x * 128;
    const int rl  = tid >> 1;
    const int kk0 = (tid & 1) * 4;

    const int m = m0 + rl;
    int arow;
    if (AMODE == 0) {
        arow = m;
    } else {
        const int q = ((m & 127) << 9) + (m >> 7);
        arow = (AMODE == 1) ? tok[q] : q;
    }
    const float* aptr = A + (size_t)arow * K;
    const int nrow = n0 + rl;
    const float* wptr = W + (size_t)nrow * K;
    const bool nvalid = (nrow < N);

    float acc[8][8];
#pragma unroll
    for (int i = 0; i < 8; ++i)
#pragma unroll
        for (int j = 0; j < 8; ++j) acc[i][j] = 0.f;

    for (int k0 = 0; k0 < K; k0 += 8) {
        float4 av = make_float4(0.f, 0.f, 0.f, 0.f);
        float4 bv = make_float4(0.f, 0.f, 0.f, 0.f);
        const bool kv = (k0 + kk0 < K);
        if (kv)           av = *(const float4*)(aptr + k0 + kk0);
        if (kv && nvalid) bv = *(const float4*)(wptr + k0 + kk0);
        __syncthreads();
        as[kk0+0][rl] = av.x; as[kk0+1][rl] = av.y; as[kk0+2][rl] = av.z; as[kk0+3][rl] = av.w;
        bs[kk0+0][rl] = bv.x; bs[kk0+1][rl] = bv.y; bs[kk0+2][rl] = bv.z; bs[kk0+3][rl] = bv.w;
        __syncthreads();
#pragma unroll
        for (int kk = 0; kk < 8; ++kk) {
            float4 a0 = *(const float4*)&as[kk][ty*8];
            float4 a1 = *(const float4*)&as[kk][ty*8+4];
            float4 c0 = *(const float4*)&bs[kk][tx*8];
            float4 c1 = *(const float4*)&bs[kk][tx*8+4];
            float a[8] = {a0.x,a0.y,a0.z,a0.w,a1.x,a1.y,a1.z,a1.w};
            float b[8] = {c0.x,c0.y,c0.z,c0.w,c1.x,c1.y,c1.z,c1.w};
#pragma unroll
            for (int i = 0; i < 8; ++i)
#pragma unroll
                for (int j = 0; j < 8; ++j)
                    acc[i][j] = fmaf(a[i], b[j], acc[i][j]);
        }
    }

    float bias[8];
#pragma unroll
    for (int j = 0; j < 8; ++j) {
        const int n = n0 + tx*8 + j;
        float v = 0.f;
        if (n < N) { v = b1[n]; if (HASB2) v += b2[n]; }
        bias[j] = v;
    }
#pragma unroll
    for (int i = 0; i < 8; ++i) {
        const int mi = m0 + ty*8 + i;
        float* orow = out + (size_t)mi * N + n0 + tx*8;
#pragma unroll
        for (int j = 0; j < 8; j += 2) {
            const int n = n0 + tx*8 + j;
            if (n + 1 < N) {
                *(float2*)(orow + j) = make_float2(acc[i][j] + bias[j],
                                                   acc[i][j+1] + bias[j+1]);
            } else if (n < N) {
                orow[j] = acc[i][j] + bias[j];
            }
        }
    }
}

// ---------------------------------------------------------------------------
// Persistent LSTM recurrence v3 — same matmul core as v2, minimal sync.
// 240 blocks = 15 hidden-groups x 16 batch-groups; batch-groups are fully
// INDEPENDENT: block (bg,hg) consumes h[t-1] only for its 8 batch rows,
// produced by the 15 blocks (bg,*). So the barrier is per-bg (15 blocks),
// not grid-wide (240) — stragglers don't couple across batch groups.
// Sync recipe per step:
//   producer: h stores = agent-scope relaxed atomics (write-through, no dirty
//     L2), __syncthreads() (drains every wave's vmcnt), tid0 publishes flag
//     with a relaxed agent store. NO __threadfence -> no buffer_wbl2 storm
//     (the round-2 regression: 3 waves x 512 steps x 240 blocks of L2
//     writebacks).
//   consumer: 15 threads poll 15 cacheline-padded flags with RELAXED atomic
//     loads (no invalidate per iteration), s_sleep(1); then ONE acquire fence
//     (single buffer_inv — needed because h rows are 1200 B, not line-aligned,
//     so L1 may hold pre-write lines fetched during step t-1's staging), then
//     plain float4 staging of h[t-1].
// ---------------------------------------------------------------------------
constexpr int HGC = 15;    // hidden groups
constexpr int BGC = 16;    // batch groups
constexpr int NWG = HGC * BGC;   // 240
constexpr int HS  = 20;    // hidden units per block
constexpr int BS  = 8;     // batch rows per block
constexpr int LTH = 256;
constexpr int WP  = 308;   // LDS pitch (floats): 16B-aligned rows, <=2-way banks
constexpr int LDSF = 80*WP + BS*WP + 4*BS*80;   // W + h + partials (floats)
constexpr int FPAD = 16;   // flag padding (u32): 64B per flag

__device__ __forceinline__ float sigm(float x)     { return 1.f / (1.f + __expf(-x)); }
__device__ __forceinline__ float tanhfast(float x) { return 1.f - 2.f / (__expf(2.f*x) + 1.f); }

__global__ __launch_bounds__(LTH)
void lstm_layer_k(const float* __restrict__ xg, const float* __restrict__ Whh,
                  float* __restrict__ h_all, unsigned* __restrict__ flags)
{
    extern __shared__ float smem[];
    float (*w_lds)[WP] = (float(*)[WP])smem;                       // [80][308]
    float (*h_lds)[WP] = (float(*)[WP])(smem + 80*WP);             // [8][308]
    float (*gp)[BS][80] = (float(*)[BS][80])(smem + 80*WP + BS*WP);// [4][8][80]

    const int tid = threadIdx.x;
    const int hg  = blockIdx.x % HGC;
    const int bg  = blockIdx.x / HGC;

    // zero all LDS (k-pad zeros + t=0 h state), then stage Whh slice
    for (int i = tid; i < LDSF; i += LTH) smem[i] = 0.f;
    __syncthreads();
    for (int idx = tid; idx < 80*75; idx += LTH) {
        const int r = idx / 75, q = (idx % 75) * 4;
        const int jglob = (r / HS) * H + hg * HS + (r % HS);
        *(float4*)&w_lds[r][q] = *(const float4*)(Whh + (size_t)jglob * H + q);
    }
    __syncthreads();

    const int lane = tid & 63;
    const int kc   = tid >> 6;          // wave id = k-chunk
    const int gg   = lane & 15;         // gate group (x5)
    const int bb   = lane >> 4;         // batch group (x2)
    const int k0   = kc * 76;

    const float* wr0 = &w_lds[gg*5+0][k0];
    const float* wr1 = &w_lds[gg*5+1][k0];
    const float* wr2 = &w_lds[gg*5+2][k0];
    const float* wr3 = &w_lds[gg*5+3][k0];
    const float* wr4 = &w_lds[gg*5+4][k0];
    const float* hr0 = &h_lds[bb*2+0][k0];
    const float* hr1 = &h_lds[bb*2+1][k0];

    const int ub = tid / HS;            // update thread -> batch row (tid<160)
    const int ul = tid % HS;            // update thread -> hidden unit
    float c = 0.f;                      // private cell state

    const unsigned* myflags = flags + (size_t)bg * HGC * FPAD;

    for (int t = 0; t < T; ++t) {
        // ---- xg prefetch for the update phase (overlaps the wait) ----
        float xr0 = 0.f, xr1 = 0.f, xr2 = 0.f, xr3 = 0.f;
        if (tid < BS*HS) {
            const float* xb = xg + ((size_t)t * B + bg*BS + ub) * G4 + hg*HS + ul;
            xr0 = xb[0*H]; xr1 = xb[1*H]; xr2 = xb[2*H]; xr3 = xb[3*H];
        }

        if (t > 0) {
            // ---- wait for the 15 producers of our batch-group ----
            if (tid < HGC) {
                const unsigned* fp = myflags + tid * FPAD;
                while (__hip_atomic_load(fp, __ATOMIC_RELAXED,
                                         __HIP_MEMORY_SCOPE_AGENT) < (unsigned)t)
                    __builtin_amdgcn_s_sleep(1);
            }
            __syncthreads();
            // one invalidate for the whole step's h loads
            __builtin_amdgcn_fence(__ATOMIC_ACQUIRE, "agent");
            // ---- stage h[t-1] for our 8 batch rows (vector loads) ----
            for (int idx = tid; idx < BS*75; idx += LTH) {
                const int b = idx / 75, q = (idx % 75) * 4;
                *(float4*)&h_lds[b][q] =
                    *(const float4*)(h_all + ((size_t)(bg*BS + b) * T + (t-1)) * H + q);
            }
        }
        __syncthreads();

        // ---- k-chunk partial matmul: 5 gates x 2 batch per lane ----
        float a00=0.f,a01=0.f,a10=0.f,a11=0.f,a20=0.f,a21=0.f,a30=0.f,a31=0.f,a40=0.f,a41=0.f;
        for (int ki = 0; ki < 19; ++ki) {
            const float4 h0 = *(const float4*)(hr0 + ki*4);
            const float4 h1 = *(const float4*)(hr1 + ki*4);
            float4 w;
            w = *(const float4*)(wr0 + ki*4);
            a00 += w.x*h0.x + w.y*h0.y + w.z*h0.z + w.w*h0.w;
            a01 += w.x*h1.x + w.y*h1.y + w.z*h1.z + w.w*h1.w;
            w = *(const float4*)(wr1 + ki*4);
            a10 += w.x*h0.x + w.y*h0.y + w.z*h0.z + w.w*h0.w;
            a11 += w.x*h1.x + w.y*h1.y + w.z*h1.z + w.w*h1.w;
            w = *(const float4*)(wr2 + ki*4);
            a20 += w.x*h0.x + w.y*h0.y + w.z*h0.z + w.w*h0.w;
            a21 += w.x*h1.x + w.y*h1.y + w.z*h1.z + w.w*h1.w;
            w = *(const float4*)(wr3 + ki*4);
            a30 += w.x*h0.x + w.y*h0.y + w.z*h0.z + w.w*h0.w;
            a31 += w.x*h1.x + w.y*h1.y + w.z*h1.z + w.w*h1.w;
            w = *(const float4*)(wr4 + ki*4);
            a40 += w.x*h0.x + w.y*h0.y + w.z*h0.z + w.w*h0.w;
            a41 += w.x*h1.x + w.y*h1.y + w.z*h1.z + w.w*h1.w;
        }
        gp[kc][bb*2+0][gg*5+0] = a00;  gp[kc][bb*2+1][gg*5+0] = a01;
        gp[kc][bb*2+0][gg*5+1] = a10;  gp[kc][bb*2+1][gg*5+1] = a11;
        gp[kc][bb*2+0][gg*5+2] = a20;  gp[kc][bb*2+1][gg*5+2] = a21;
        gp[kc][bb*2+0][gg*5+3] = a30;  gp[kc][bb*2+1][gg*5+3] = a31;
        gp[kc][bb*2+0][gg*5+4] = a40;  gp[kc][bb*2+1][gg*5+4] = a41;
        __syncthreads();

        // ---- reduce + activations + cell update (one (b,l) per thread) ----
        if (tid < BS*HS) {
            const float g0 = xr0 + gp[0][ub][0*HS+ul] + gp[1][ub][0*HS+ul]
                                 + gp[2][ub][0*HS+ul] + gp[3][ub][0*HS+ul];
            const float g1 = xr1 + gp[0][ub][1*HS+ul] + gp[1][ub][1*HS+ul]
                                 + gp[2][ub][1*HS+ul] + gp[3][ub][1*HS+ul];
            const float g2 = xr2 + gp[0][ub][2*HS+ul] + gp[1][ub][2*HS+ul]
                                 + gp[2][ub][2*HS+ul] + gp[3][ub][2*HS+ul];
            const float g3 = xr3 + gp[0][ub][3*HS+ul] + gp[1][ub][3*HS+ul]
                                 + gp[2][ub][3*HS+ul] + gp[3][ub][3*HS+ul];
            const float iG = sigm(g0), fG = sigm(g1), gG = tanhfast(g2), oG = sigm(g3);
            c = fmaf(fG, c, iG * gG);
            const float hv = oG * tanhfast(c);
            float* p = h_all + ((size_t)(bg*BS + ub) * T + t) * H + hg*HS + ul;
            __hip_atomic_store(p, hv, __ATOMIC_RELAXED, __HIP_MEMORY_SCOPE_AGENT);
        }
        // drains every wave's vmcnt before any thread passes -> all h stores
        // of this block are at the coherent point before the flag publish
        __syncthreads();
        if (tid == 0)
            __hip_atomic_store((unsigned*)(myflags + hg * FPAD), (unsigned)(t + 1),
                               __ATOMIC_RELAXED, __HIP_MEMORY_SCOPE_AGENT);
    }
}

} // anonymous namespace

// ---------------------------------------------------------------------------
extern "C" void kernel_launch(void* const* d_in, const int* in_sizes, int n_in,
                              void* d_out, int out_size, void* d_ws, size_t ws_size,
                              hipStream_t stream)
{
    const int*   x    = (const int*)  d_in[0];
    const float* emb  = (const float*)d_in[1];
    const float* Wih0 = (const float*)d_in[2];
    const float* Whh0 = (const float*)d_in[3];
    const float* bih0 = (const float*)d_in[4];
    const float* bhh0 = (const float*)d_in[5];
    const float* Wih1 = (const float*)d_in[6];
    const float* Whh1 = (const float*)d_in[7];
    const float* bih1 = (const float*)d_in[8];
    const float* bhh1 = (const float*)d_in[9];
    const float* Wout = (const float*)d_in[10];
    const float* bout = (const float*)d_in[11];

    float* out = (float*)d_out;
    // xg [T][B][4H] fp32 (315 MB) aliases the output buffer (659 MB): fully
    // consumed before the final GEMM overwrites d_out.
    float* xg = (float*)d_out;
    float* h1 = (float*)d_ws;                       // [B][T][H] fp32, 78.6 MB
    float* h2 = h1 + (size_t)B * T * H;             // 78.6 MB
    unsigned* flags = (unsigned*)((char*)d_ws + 2 * (size_t)B * T * H * sizeof(float));
    constexpr size_t flags_per_layer = (size_t)NWG * FPAD;   // 240*16 u32 = 15 KiB

    hipMemsetAsync(flags, 0, 2 * flags_per_layer * sizeof(unsigned), stream);

    constexpr size_t lstm_lds = (size_t)LDSF * sizeof(float);   // 118,656 B
    static_assert(lstm_lds < 160*1024, "LDS over budget");
    hipFuncSetAttribute(reinterpret_cast<const void*>(lstm_layer_k),
                        hipFuncAttributeMaxDynamicSharedMemorySize, (int)lstm_lds);

    const dim3 blk(256);
    // L0 input projection (embedding gather fused)
    gemm_tn<1, true ><<<dim3(10, 512), blk, 0, stream>>>(emb, Wih0, bih0, bhh0, x, xg, G4);
    // L0 recurrence
    lstm_layer_k<<<dim3(NWG), dim3(LTH), lstm_lds, stream>>>(xg, Whh0, h1, flags);
    // L1 input projection ([b][t] -> [t][b] permute fused)
    gemm_tn<2, true ><<<dim3(10, 512), blk, 0, stream>>>(h1, Wih1, bih1, bhh1, nullptr, xg, G4);
    // L1 recurrence
    lstm_layer_k<<<dim3(NWG), dim3(LTH), lstm_lds, stream>>>(xg, Whh1, h2,
                                                             flags + flags_per_layer);
    // output projection -> logits [b*T+t][NVOC]
    gemm_tn<0, false><<<dim3(20, 512), blk, 0, stream>>>(h2, Wout, bout, nullptr, nullptr, out, NVOC);
}

// Round 4
// 7901.810 us; speedup vs baseline: 4.9357x; 1.3670x over previous
//
#include <hip/hip_runtime.h>
#include <cstdint>
#include <cstddef>

namespace {

constexpr int H    = 300;
constexpr int G4   = 1200;   // 4*H
constexpr int B    = 128;
constexpr int T    = 512;
constexpr int NVOC = 2514;

// ---------------------------------------------------------------------------
// Tiled fp32 GEMM:  out[m][n] = sum_k A[row(m)][k] * W[n][k] + b1[n] (+ b2[n])
// AMODE 0: row = m
// AMODE 1: row = tok[(m&127)*512 + (m>>7)]   (embedding gather, m = t*128+b)
// AMODE 2: row = (m&127)*512 + (m>>7)        ([t,b] -> [b,t] permute)
// (unchanged — ~2.1 ms total; LSTM still dominates)
// ---------------------------------------------------------------------------
template<int AMODE, bool HASB2>
__global__ __launch_bounds__(256)
void gemm_tn(const float* __restrict__ A, const float* __restrict__ W,
             const float* __restrict__ b1, const float* __restrict__ b2,
             const int* __restrict__ tok, float* __restrict__ out, int N)
{
    constexpr int K = 300;
    __shared__ __align__(16) float as[8][128];
    __shared__ __align__(16) float bs[8][128];

    const int tid = threadIdx.x;
    const int tx = tid & 15, ty = tid >> 4;
    const int m0 = blockIdx.y * 128;
    const int n0 = blockIdx.x * 128;
    const int rl  = tid >> 1;
    const int kk0 = (tid & 1) * 4;

    const int m = m0 + rl;
    int arow;
    if (AMODE == 0) {
        arow = m;
    } else {
        const int q = ((m & 127) << 9) + (m >> 7);
        arow = (AMODE == 1) ? tok[q] : q;
    }
    const float* aptr = A + (size_t)arow * K;
    const int nrow = n0 + rl;
    const float* wptr = W + (size_t)nrow * K;
    const bool nvalid = (nrow < N);

    float acc[8][8];
#pragma unroll
    for (int i = 0; i < 8; ++i)
#pragma unroll
        for (int j = 0; j < 8; ++j) acc[i][j] = 0.f;

    for (int k0 = 0; k0 < K; k0 += 8) {
        float4 av = make_float4(0.f, 0.f, 0.f, 0.f);
        float4 bv = make_float4(0.f, 0.f, 0.f, 0.f);
        const bool kv = (k0 + kk0 < K);
        if (kv)           av = *(const float4*)(aptr + k0 + kk0);
        if (kv && nvalid) bv = *(const float4*)(wptr + k0 + kk0);
        __syncthreads();
        as[kk0+0][rl] = av.x; as[kk0+1][rl] = av.y; as[kk0+2][rl] = av.z; as[kk0+3][rl] = av.w;
        bs[kk0+0][rl] = bv.x; bs[kk0+1][rl] = bv.y; bs[kk0+2][rl] = bv.z; bs[kk0+3][rl] = bv.w;
        __syncthreads();
#pragma unroll
        for (int kk = 0; kk < 8; ++kk) {
            float4 a0 = *(const float4*)&as[kk][ty*8];
            float4 a1 = *(const float4*)&as[kk][ty*8+4];
            float4 c0 = *(const float4*)&bs[kk][tx*8];
            float4 c1 = *(const float4*)&bs[kk][tx*8+4];
            float a[8] = {a0.x,a0.y,a0.z,a0.w,a1.x,a1.y,a1.z,a1.w};
            float b[8] = {c0.x,c0.y,c0.z,c0.w,c1.x,c1.y,c1.z,c1.w};
#pragma unroll
            for (int i = 0; i < 8; ++i)
#pragma unroll
                for (int j = 0; j < 8; ++j)
                    acc[i][j] = fmaf(a[i], b[j], acc[i][j]);
        }
    }

    float bias[8];
#pragma unroll
    for (int j = 0; j < 8; ++j) {
        const int n = n0 + tx*8 + j;
        float v = 0.f;
        if (n < N) { v = b1[n]; if (HASB2) v += b2[n]; }
        bias[j] = v;
    }
#pragma unroll
    for (int i = 0; i < 8; ++i) {
        const int mi = m0 + ty*8 + i;
        float* orow = out + (size_t)mi * N + n0 + tx*8;
#pragma unroll
        for (int j = 0; j < 8; j += 2) {
            const int n = n0 + tx*8 + j;
            if (n + 1 < N) {
                *(float2*)(orow + j) = make_float2(acc[i][j] + bias[j],
                                                   acc[i][j+1] + bias[j+1]);
            } else if (n < N) {
                orow[j] = acc[i][j] + bias[j];
            }
        }
    }
}

// ---------------------------------------------------------------------------
// Sentinel fill: h buffers pre-filled with a NaN pattern each call.
// h = sigm*tanh in (-1,1) can never be NaN -> data doubles as the ready flag.
// ---------------------------------------------------------------------------
constexpr unsigned SENT = 0x7FB00F0Fu;   // quiet NaN payload

__global__ __launch_bounds__(256)
void sentinel_fill(uint4* __restrict__ p, size_t n4)
{
    const uint4 s = make_uint4(SENT, SENT, SENT, SENT);
    size_t i = (size_t)blockIdx.x * blockDim.x + threadIdx.x;
    const size_t stride = (size_t)gridDim.x * blockDim.x;
    for (; i < n4; i += stride) p[i] = s;
}

// ---------------------------------------------------------------------------
// Persistent LSTM recurrence v4 — wave-autonomous, data-as-flag sync.
// 240 blocks = 15 hidden-groups x 16 batch-groups, 4 waves each.
// Wave wv owns 2 batch rows (2wv, 2wv+1 within the block's 8) END-TO-END:
//   - polls its 600 h[t-1] values directly (8B relaxed agent atomic loads,
//     != sentinel), ds_writes them into its own h_lds rows
//   - matmul: lane=(gg 0..15, ks 0..3): intra-wave k-split (4 x 76), per-lane
//     tile 5 gate-cols x 2 batch; w-read pattern = 64 distinct addresses/instr
//     (exactly 8 dwords/bank @ pitch 308 -> conflict-free)
//   - k-partials reduced with 2x shfl_xor (16, 32) — no cross-wave exchange
//   - lanes<40 do activations + private cell state + relaxed agent h store
// ZERO __syncthreads in the step loop; no flags, no fences. Sync latency =
// one-way store propagation + poll pickup (round 3 had 2 serialized RTs).
// ---------------------------------------------------------------------------
constexpr int HGC = 15;    // hidden groups
constexpr int BGC = 16;    // batch groups
constexpr int NWG = HGC * BGC;   // 240
constexpr int HS  = 20;    // hidden units per block
constexpr int BS  = 8;     // batch rows per block
constexpr int LTH = 256;
constexpr int WP  = 308;   // LDS pitch (floats)
constexpr int LDSF = 80*WP + BS*WP + 4*2*80;   // W + h + per-wave partials

__device__ __forceinline__ float sigm(float x)     { return 1.f / (1.f + __expf(-x)); }
__device__ __forceinline__ float tanhfast(float x) { return 1.f - 2.f / (__expf(2.f*x) + 1.f); }

__global__ __launch_bounds__(LTH)
void lstm_layer_k(const float* __restrict__ xg, const float* __restrict__ Whh,
                  float* __restrict__ h_all)
{
    extern __shared__ float smem[];
    float (*w_lds)[WP]    = (float(*)[WP])smem;                     // [80][308]
    float (*h_lds)[WP]    = (float(*)[WP])(smem + 80*WP);           // [8][308]
    float (*gp)[2][80]    = (float(*)[2][80])(smem + 80*WP + BS*WP);// [4][2][80]

    const int tid = threadIdx.x;
    const int hg  = blockIdx.x % HGC;
    const int bg  = blockIdx.x / HGC;

    // zero LDS (k-pad zeros + t=0 h state), then stage Whh slice
    for (int i = tid; i < LDSF; i += LTH) smem[i] = 0.f;
    __syncthreads();
    for (int idx = tid; idx < 80*75; idx += LTH) {
        const int r = idx / 75, q = (idx % 75) * 4;
        const int jglob = (r / HS) * H + hg * HS + (r % HS);
        *(float4*)&w_lds[r][q] = *(const float4*)(Whh + (size_t)jglob * H + q);
    }
    __syncthreads();   // the only block-wide syncs in the kernel

    const int wv   = tid >> 6;          // wave id -> owns local batch {2wv,2wv+1}
    const int lane = tid & 63;
    const int gg   = lane & 15;         // gate-col group (x5)
    const int ks   = lane >> 4;         // intra-wave k-chunk
    const int k0   = ks * 76;

    const float* wr0 = &w_lds[gg*5+0][k0];
    const float* wr1 = &w_lds[gg*5+1][k0];
    const float* wr2 = &w_lds[gg*5+2][k0];
    const float* wr3 = &w_lds[gg*5+3][k0];
    const float* wr4 = &w_lds[gg*5+4][k0];
    const float* hrA = &h_lds[2*wv+0][k0];
    const float* hrB = &h_lds[2*wv+1][k0];

    // poll slots: element-pair e2 = lane + 64*j (j=0..4), e2 < 300
    // row = e2/150 (local batch offset 0/1), col2 = e2%150
    const int e2_0 = lane,       r_0 = e2_0/150, c_0 = (e2_0%150)*2;
    const int e2_1 = lane+ 64,   r_1 = e2_1/150, c_1 = (e2_1%150)*2;
    const int e2_2 = lane+128,   r_2 = e2_2/150, c_2 = (e2_2%150)*2;
    const int e2_3 = lane+192,   r_3 = e2_3/150, c_3 = (e2_3%150)*2;
    const int e2_4 = lane+256,   r_4 = e2_4/150, c_4 = (e2_4%150)*2;
    float2* d0 = (float2*)&h_lds[2*wv+r_0][c_0];
    float2* d1 = (float2*)&h_lds[2*wv+r_1][c_1];
    float2* d2 = (float2*)&h_lds[2*wv+r_2][c_2];
    float2* d3 = (float2*)&h_lds[2*wv+r_3][c_3];
    float2* d4 = (float2*)&h_lds[2*wv+r_4][c_4];
    const unsigned pend0 = (lane < 44) ? 0x1Fu : 0x0Fu;   // j=4 only for e2<300

    // update mapping (lanes < 40): local batch 2wv+ub, hidden unit ul
    const int ub = lane / HS;       // 0..1 (lanes 0..39)
    const int ul = lane % HS;
    float c = 0.f;                  // private cell state

    const size_t TH = (size_t)T * H;
    const float* hrowA = h_all + ((size_t)(bg*BS + 2*wv) * T) * H;   // batch 2wv, t=0

    for (int t = 0; t < T; ++t) {
        // xg prefetch (overlaps poll latency)
        float xr0 = 0.f, xr1 = 0.f, xr2 = 0.f, xr3 = 0.f;
        if (lane < BS/4*HS /*40*/) {
            const float* xb = xg + ((size_t)t * B + bg*BS + 2*wv + ub) * G4 + hg*HS + ul;
            xr0 = xb[0*H]; xr1 = xb[1*H]; xr2 = xb[2*H]; xr3 = xb[3*H];
        }

        if (t > 0) {
            // poll h[t-1] for our 2 batch rows until != sentinel (data IS the flag)
            const char* sbase = (const char*)(hrowA + (size_t)(t-1) * H);
            const unsigned long long* s0 = (const unsigned long long*)(sbase + ((size_t)r_0*TH)*4) + (c_0>>1);
            const unsigned long long* s1 = (const unsigned long long*)(sbase + ((size_t)r_1*TH)*4) + (c_1>>1);
            const unsigned long long* s2 = (const unsigned long long*)(sbase + ((size_t)r_2*TH)*4) + (c_2>>1);
            const unsigned long long* s3 = (const unsigned long long*)(sbase + ((size_t)r_3*TH)*4) + (c_3>>1);
            const unsigned long long* s4 = (const unsigned long long*)(sbase + ((size_t)r_4*TH)*4) + (c_4>>1);
            unsigned pend = pend0;
            while (pend) {
#define POLL(J, SJ, DJ)                                                          \
                if (pend & (1u << J)) {                                          \
                    unsigned long long v = __hip_atomic_load(SJ, __ATOMIC_RELAXED, \
                                               __HIP_MEMORY_SCOPE_AGENT);        \
                    if ((unsigned)v != SENT && (unsigned)(v >> 32) != SENT) {    \
                        *DJ = make_float2(__uint_as_float((unsigned)v),          \
                                          __uint_as_float((unsigned)(v >> 32))); \
                        pend &= ~(1u << J);                                      \
                    }                                                            \
                }
                POLL(0, s0, d0) POLL(1, s1, d1) POLL(2, s2, d2)
                POLL(3, s3, d3) POLL(4, s4, d4)
#undef POLL
            }
        }
        // same-wave ds_write -> ds_read: program order + lgkmcnt (no barrier)

        // ---- matmul: per-lane 5 gate-cols x 2 batch over k-chunk 76 ----
        float a00=0.f,a01=0.f,a10=0.f,a11=0.f,a20=0.f,a21=0.f,a30=0.f,a31=0.f,a40=0.f,a41=0.f;
        for (int ki = 0; ki < 19; ++ki) {
            const float4 h0 = *(const float4*)(hrA + ki*4);
            const float4 h1 = *(const float4*)(hrB + ki*4);
            float4 w;
            w = *(const float4*)(wr0 + ki*4);
            a00 += w.x*h0.x + w.y*h0.y + w.z*h0.z + w.w*h0.w;
            a01 += w.x*h1.x + w.y*h1.y + w.z*h1.z + w.w*h1.w;
            w = *(const float4*)(wr1 + ki*4);
            a10 += w.x*h0.x + w.y*h0.y + w.z*h0.z + w.w*h0.w;
            a11 += w.x*h1.x + w.y*h1.y + w.z*h1.z + w.w*h1.w;
            w = *(const float4*)(wr2 + ki*4);
            a20 += w.x*h0.x + w.y*h0.y + w.z*h0.z + w.w*h0.w;
            a21 += w.x*h1.x + w.y*h1.y + w.z*h1.z + w.w*h1.w;
            w = *(const float4*)(wr3 + ki*4);
            a30 += w.x*h0.x + w.y*h0.y + w.z*h0.z + w.w*h0.w;
            a31 += w.x*h1.x + w.y*h1.y + w.z*h1.z + w.w*h1.w;
            w = *(const float4*)(wr4 + ki*4);
            a40 += w.x*h0.x + w.y*h0.y + w.z*h0.z + w.w*h0.w;
            a41 += w.x*h1.x + w.y*h1.y + w.z*h1.z + w.w*h1.w;
        }

        // ---- intra-wave k-reduction: sum over ks (lane bits 4,5) ----
#define RED(A) A += __shfl_xor(A, 16, 64); A += __shfl_xor(A, 32, 64);
        RED(a00) RED(a01) RED(a10) RED(a11) RED(a20)
        RED(a21) RED(a30) RED(a31) RED(a40) RED(a41)
#undef RED

        // ---- wave-local gate exchange (ks==0 lanes hold the full sums) ----
        if (ks == 0) {
            float* g0 = &gp[wv][0][gg*5];
            float* g1 = &gp[wv][1][gg*5];
            g0[0]=a00; g0[1]=a10; g0[2]=a20; g0[3]=a30; g0[4]=a40;
            g1[0]=a01; g1[1]=a11; g1[2]=a21; g1[3]=a31; g1[4]=a41;
        }
        // same-wave LDS ordering; compiler inserts lgkmcnt before the reads

        // ---- activations + cell update + publish (lanes 0..39) ----
        if (lane < 40) {
            const float gi = xr0 + gp[wv][ub][0*HS + ul];
            const float gf = xr1 + gp[wv][ub][1*HS + ul];
            const float gz = xr2 + gp[wv][ub][2*HS + ul];
            const float go = xr3 + gp[wv][ub][3*HS + ul];
            const float iG = sigm(gi), fG = sigm(gf), zG = tanhfast(gz), oG = sigm(go);
            c = fmaf(fG, c, iG * zG);
            const float hv = oG * tanhfast(c);
            float* p = h_all + ((size_t)(bg*BS + 2*wv + ub) * T + t) * H + hg*HS + ul;
            __hip_atomic_store(p, hv, __ATOMIC_RELAXED, __HIP_MEMORY_SCOPE_AGENT);
        }
    }
}

} // anonymous namespace

// ---------------------------------------------------------------------------
extern "C" void kernel_launch(void* const* d_in, const int* in_sizes, int n_in,
                              void* d_out, int out_size, void* d_ws, size_t ws_size,
                              hipStream_t stream)
{
    const int*   x    = (const int*)  d_in[0];
    const float* emb  = (const float*)d_in[1];
    const float* Wih0 = (const float*)d_in[2];
    const float* Whh0 = (const float*)d_in[3];
    const float* bih0 = (const float*)d_in[4];
    const float* bhh0 = (const float*)d_in[5];
    const float* Wih1 = (const float*)d_in[6];
    const float* Whh1 = (const float*)d_in[7];
    const float* bih1 = (const float*)d_in[8];
    const float* bhh1 = (const float*)d_in[9];
    const float* Wout = (const float*)d_in[10];
    const float* bout = (const float*)d_in[11];

    float* out = (float*)d_out;
    // xg [T][B][4H] fp32 (315 MB) aliases the output buffer (659 MB): fully
    // consumed before the final GEMM overwrites d_out.
    float* xg = (float*)d_out;
    float* h1 = (float*)d_ws;                       // [B][T][H] fp32, 78.6 MB
    float* h2 = h1 + (size_t)B * T * H;             // 78.6 MB

    // sentinel-fill both h buffers (data-as-flag protocol), ~157 MB ≈ 25 µs
    const size_t nh = 2 * (size_t)B * T * H;        // floats (multiple of 4)
    sentinel_fill<<<dim3(2048), dim3(256), 0, stream>>>((uint4*)h1, nh / 4);

    constexpr size_t lstm_lds = (size_t)LDSF * sizeof(float);   // 110,976 B
    static_assert(lstm_lds < 160*1024, "LDS over budget");
    hipFuncSetAttribute(reinterpret_cast<const void*>(lstm_layer_k),
                        hipFuncAttributeMaxDynamicSharedMemorySize, (int)lstm_lds);

    const dim3 blk(256);
    // L0 input projection (embedding gather fused)
    gemm_tn<1, true ><<<dim3(10, 512), blk, 0, stream>>>(emb, Wih0, bih0, bhh0, x, xg, G4);
    // L0 recurrence
    lstm_layer_k<<<dim3(NWG), dim3(LTH), lstm_lds, stream>>>(xg, Whh0, h1);
    // L1 input projection ([b][t] -> [t][b] permute fused)
    gemm_tn<2, true ><<<dim3(10, 512), blk, 0, stream>>>(h1, Wih1, bih1, bhh1, nullptr, xg, G4);
    // L1 recurrence
    lstm_layer_k<<<dim3(NWG), dim3(LTH), lstm_lds, stream>>>(xg, Whh1, h2);
    // output projection -> logits [b*T+t][NVOC]
    gemm_tn<0, false><<<dim3(20, 512), blk, 0, stream>>>(h2, Wout, bout, nullptr, nullptr, out, NVOC);
}